// Round 3
// baseline (241.494 us; speedup 1.0000x reference)
//
#include <hip/hip_runtime.h>

#define EPS 1e-8f

// ---------------------------------------------------------------------------
// Single-kernel chunked scan with decoupled lookback.
// Block = (chunk c, group g of 256 chains). Chains indexed bf in [0, B*F).
// Phase 1: zero-carry local scan, locals kept in registers (lv[L], static
//          indexing via full unroll), publish chunk aggregate + flag.
// Lookback: wait for all predecessors' aggregates (agent-scope atomics,
//          cross-XCD safe), Horner-combine into exact carry-in.
// Phase 2: recover power from consecutive locals (no re-read of mag!),
//          smooth_t = lv[t] + (1-a)^(t+1) * carry, write normalized output.
// mag read once, out written once -> compulsory-traffic roofline.
// ---------------------------------------------------------------------------
template <int L>
__global__ __launch_bounds__(256, 4)
void fns3_scan(const float* __restrict__ mag,
               const float* __restrict__ s0,
               const float* __restrict__ weights,
               const float* __restrict__ bias,
               const float* __restrict__ alpha,
               float* __restrict__ out,
               int* __restrict__ flags,   // [C][NG], zeroed before launch
               float* __restrict__ S,     // [C][BF] chunk aggregates
               int B, int T, int F, int C, int NG) {
    const int BF = B * F;
    const int c  = blockIdx.x / NG;          // chunk index (slow -> dispatch order)
    const int g  = blockIdx.x - c * NG;      // chain-group index
    const int bf = g * 256 + threadIdx.x;
    const bool valid = bf < BF;
    const int b = valid ? bf / F : 0;
    const int f = valid ? bf - b * F : 0;

    const float a   = 1.0f / (1.0f + expf(-alpha[f]));
    const float oma = 1.0f - a;
    const float w   = weights[f];
    const float bi  = bias[f];

    const int t0 = c * L;
    const float* p = mag + ((size_t)b * T + t0) * F + f;

    // ---- phase 1: zero-carry local scan, locals in registers ----
    float lv[L];
    float local = 0.0f;
#pragma unroll
    for (int t = 0; t < L; ++t) {
        float m = valid ? p[(size_t)t * F] : 0.0f;
        local = local * oma + (m * m) * a;    // exact reference recurrence form
        lv[t] = local;
    }

    // ---- publish aggregate, then flag (release, device scope) ----
    if (valid)
        __hip_atomic_store(&S[(size_t)c * BF + bf], local,
                           __ATOMIC_RELAXED, __HIP_MEMORY_SCOPE_AGENT);
    __threadfence();
    __syncthreads();
    if (threadIdx.x == 0)
        __hip_atomic_store(&flags[c * NG + g], 1,
                           __ATOMIC_RELEASE, __HIP_MEMORY_SCOPE_AGENT);

    // ---- lookback: wait for all predecessor aggregates of this group ----
    float x = valid ? s0[bf] : 0.0f;          // running carry
    if (c > 0) {
        const int j = threadIdx.x;            // thread j watches flag j (c <= 255)
        bool mine = (j >= c);
        while (true) {
            if (!mine)
                mine = __hip_atomic_load(&flags[j * NG + g],
                                         __ATOMIC_ACQUIRE, __HIP_MEMORY_SCOPE_AGENT) != 0;
            if (__syncthreads_and((int)mine)) break;
            __builtin_amdgcn_s_sleep(8);
        }
        const float D = powf(oma, (float)L);  // per-chunk decay
        for (int jj = 0; jj < c; ++jj) {      // Horner: identical to old pass2
            float Sv = valid
                ? __hip_atomic_load(&S[(size_t)jj * BF + bf],
                                    __ATOMIC_RELAXED, __HIP_MEMORY_SCOPE_AGENT)
                : 0.0f;
            x = x * D + Sv;
        }
    }

    // ---- phase 2: recover power, normalize, write (no mag re-read) ----
    const float ra = 1.0f / a;
    float Dt   = 1.0f;
    float prev = 0.0f;
    float* o = out + ((size_t)b * T + t0) * F + f;
#pragma unroll
    for (int t = 0; t < L; ++t) {
        float pw = (lv[t] - prev * oma) * ra; // power_t, few-ulp recovery
        pw = fmaxf(pw, 0.0f);                 // clamp rounding-negative
        float m  = sqrtf(pw);                 // mag_t (mag >= 0)
        Dt *= oma;                            // (1-a)^(t+1)
        float smooth = fmaf(Dt, x, lv[t]);    // both terms >= 0, no cancellation
        float denom  = sqrtf(smooth) + EPS;
        if (valid)
            o[(size_t)t * F] = m * __builtin_amdgcn_rcpf(denom) * w + bi;
        prev = lv[t];
    }
}

// ---------------------------------------------------------------------------
// Fallback: one thread per (b,f) chain (used only if ws too small or odd T).
// ---------------------------------------------------------------------------
__global__ void fns3_fallback(const float* __restrict__ mag,
                              const float* __restrict__ s0,
                              const float* __restrict__ weights,
                              const float* __restrict__ bias,
                              const float* __restrict__ alpha,
                              float* __restrict__ out,
                              int B, int T, int F) {
    int bf = blockIdx.x * blockDim.x + threadIdx.x;
    int BF = B * F;
    if (bf >= BF) return;
    int b = bf / F;
    int f = bf - b * F;

    float a  = 1.0f / (1.0f + expf(-alpha[f]));
    float w  = weights[f];
    float bi = bias[f];

    float carry = s0[bf];
    const float* p = mag + (size_t)b * T * F + f;
    float*       o = out + (size_t)b * T * F + f;

    for (int t = 0; t < T; ++t) {
        float m = p[(size_t)t * F];
        carry = carry * (1.0f - a) + (m * m) * a;
        o[(size_t)t * F] = m / (sqrtf(carry) + EPS) * w + bi;
    }
}

extern "C" void kernel_launch(void* const* d_in, const int* in_sizes, int n_in,
                              void* d_out, int out_size, void* d_ws, size_t ws_size,
                              hipStream_t stream) {
    const float* mag     = (const float*)d_in[0];
    const float* s0      = (const float*)d_in[1];
    const float* weights = (const float*)d_in[2];
    const float* bias    = (const float*)d_in[3];
    const float* alpha   = (const float*)d_in[4];
    float* out = (float*)d_out;

    int F  = in_sizes[4];          // alpha is [1, F]
    int BF = in_sizes[1];          // s is [B, F]
    int B  = BF / F;
    int T  = in_sizes[0] / BF;     // mag is [B, T, F]

    constexpr int L = 50;          // chunk length (compile-time for full unroll)
    if (T % L == 0) {
        int C  = T / L;            // 20 for T=1000
        int NG = (BF + 255) / 256; // 65
        if (C <= 256) {            // lookback watches one flag per thread
            size_t flagsBytes = (size_t)C * NG * sizeof(int);
            size_t sOff = (flagsBytes + 255) & ~(size_t)255;
            size_t need = sOff + (size_t)C * BF * sizeof(float);
            if (ws_size >= need) {
                int*   flags = (int*)d_ws;
                float* S     = (float*)((char*)d_ws + sOff);
                hipMemsetAsync(flags, 0, flagsBytes, stream);
                fns3_scan<L><<<C * NG, 256, 0, stream>>>(
                    mag, s0, weights, bias, alpha, out, flags, S,
                    B, T, F, C, NG);
                return;
            }
        }
    }

    int threads = 256;
    int blocks  = (BF + threads - 1) / threads;
    fns3_fallback<<<blocks, threads, 0, stream>>>(mag, s0, weights, bias,
                                                  alpha, out, B, T, F);
}

// Round 4
// 46.643 us; speedup vs baseline: 5.1774x; 5.1774x over previous
//
#include <hip/hip_runtime.h>

#define EPS 1e-8f

// ---------------------------------------------------------------------------
// Two-kernel chunked scan. No LDS, no atomics, no cross-block sync.
// Chains (b,f) laid out as bf in [0,BF); time split into C chunks of L.
// Thread (bf, c) owns chunk c of chain bf. Consecutive threads -> consecutive
// bf -> fully wave-coalesced loads/stores at every time step.
// ---------------------------------------------------------------------------

// k1: zero-carry local scan of chunk c, store chunk-end aggregate S[c][bf].
template <int L>
__global__ __launch_bounds__(256)
void fns4_aggregate(const float* __restrict__ mag,
                    const float* __restrict__ alpha,
                    float* __restrict__ S,   // [C][BF]
                    int B, int T, int F, int C) {
    const int BF = B * F;
    int g = blockIdx.x * blockDim.x + threadIdx.x;
    if (g >= BF * C) return;
    const int bf = g % BF;
    const int c  = g / BF;
    const int b  = bf / F;
    const int f  = bf - b * F;

    const float a   = 1.0f / (1.0f + expf(-alpha[f]));
    const float oma = 1.0f - a;

    const float* p = mag + ((size_t)b * T + (size_t)c * L) * F + f;

    float local = 0.0f;
#pragma unroll
    for (int t = 0; t < L; ++t) {
        float m = p[(size_t)t * F];
        local = local * oma + (m * m) * a;   // exact reference recurrence form
    }
    S[(size_t)c * BF + bf] = local;
}

// k2: reconstruct exact carry-in from s0 + preceding aggregates (Horner,
// identical arithmetic to a sequential middle pass), then scan + normalize.
template <int L>
__global__ __launch_bounds__(256)
void fns4_emit(const float* __restrict__ mag,
               const float* __restrict__ s0,
               const float* __restrict__ weights,
               const float* __restrict__ bias,
               const float* __restrict__ alpha,
               const float* __restrict__ S,   // [C][BF]
               float* __restrict__ out,
               int B, int T, int F, int C) {
    const int BF = B * F;
    int g = blockIdx.x * blockDim.x + threadIdx.x;
    if (g >= BF * C) return;
    const int bf = g % BF;
    const int c  = g / BF;
    const int b  = bf / F;
    const int f  = bf - b * F;

    const float a   = 1.0f / (1.0f + expf(-alpha[f]));
    const float oma = 1.0f - a;
    const float w   = weights[f];
    const float bi  = bias[f];

    // carry-in for chunk c (all preceding chunks have full length L)
    float carry = s0[bf];
    if (c > 0) {
        const float D = powf(oma, (float)L);
        for (int j = 0; j < c; ++j)
            carry = carry * D + S[(size_t)j * BF + bf];
    }

    const float* p = mag + ((size_t)b * T + (size_t)c * L) * F + f;
    float*       o = out + ((size_t)b * T + (size_t)c * L) * F + f;

#pragma unroll
    for (int t = 0; t < L; ++t) {
        float m = p[(size_t)t * F];
        carry = carry * oma + (m * m) * a;
        o[(size_t)t * F] = m / (sqrtf(carry) + EPS) * w + bi;
    }
}

// ---------------------------------------------------------------------------
// Fallback: one thread per (b,f) chain (general shapes / tiny workspace).
// ---------------------------------------------------------------------------
__global__ void fns4_fallback(const float* __restrict__ mag,
                              const float* __restrict__ s0,
                              const float* __restrict__ weights,
                              const float* __restrict__ bias,
                              const float* __restrict__ alpha,
                              float* __restrict__ out,
                              int B, int T, int F) {
    int bf = blockIdx.x * blockDim.x + threadIdx.x;
    int BF = B * F;
    if (bf >= BF) return;
    int b = bf / F;
    int f = bf - b * F;

    float a  = 1.0f / (1.0f + expf(-alpha[f]));
    float w  = weights[f];
    float bi = bias[f];

    float carry = s0[bf];
    const float* p = mag + (size_t)b * T * F + f;
    float*       o = out + (size_t)b * T * F + f;

    for (int t = 0; t < T; ++t) {
        float m = p[(size_t)t * F];
        carry = carry * (1.0f - a) + (m * m) * a;
        o[(size_t)t * F] = m / (sqrtf(carry) + EPS) * w + bi;
    }
}

extern "C" void kernel_launch(void* const* d_in, const int* in_sizes, int n_in,
                              void* d_out, int out_size, void* d_ws, size_t ws_size,
                              hipStream_t stream) {
    const float* mag     = (const float*)d_in[0];
    const float* s0      = (const float*)d_in[1];
    const float* weights = (const float*)d_in[2];
    const float* bias    = (const float*)d_in[3];
    const float* alpha   = (const float*)d_in[4];
    float* out = (float*)d_out;

    int F  = in_sizes[4];          // alpha is [1, F]
    int BF = in_sizes[1];          // s is [B, F]
    int B  = BF / F;
    int T  = in_sizes[0] / BF;     // mag is [B, T, F]

    constexpr int L = 50;          // compile-time chunk length (full unroll)
    if (T % L == 0) {
        int C = T / L;             // 20 for T=1000
        size_t need = (size_t)C * BF * sizeof(float);
        if (ws_size >= need) {
            float* S = (float*)d_ws;
            int total  = BF * C;   // 328,960
            int blocks = (total + 255) / 256;
            fns4_aggregate<L><<<blocks, 256, 0, stream>>>(
                mag, alpha, S, B, T, F, C);
            fns4_emit<L><<<blocks, 256, 0, stream>>>(
                mag, s0, weights, bias, alpha, S, out, B, T, F, C);
            return;
        }
    }

    int threads = 256;
    int blocks  = (BF + threads - 1) / threads;
    fns4_fallback<<<blocks, threads, 0, stream>>>(mag, s0, weights, bias,
                                                  alpha, out, B, T, F);
}